// Round 5
// baseline (364.681 us; speedup 1.0000x reference)
//
#include <hip/hip_runtime.h>
#include <math.h>

#if __has_builtin(__builtin_amdgcn_exp2f)
#define EXP2(x) __builtin_amdgcn_exp2f(x)
#else
#define EXP2(x) exp2f(x)
#endif

#define ALPHA_LRELU 0.2f
#define LOG2E 1.4426950408889634f
#define ESHIFT 6.0f
#define BIGM 1024.0f  // bit=0 -> exp2 arg < -1000 -> p = 0

#define AGS __HIP_MEMORY_SCOPE_AGENT

constexpr int Bc = 2, Nn = 2048, Ff = 256, Hh = 8, Oo = 32;
constexpr unsigned GRID_BLKS = 1024;

typedef _Float16 f16;
typedef f16 f16x8 __attribute__((ext_vector_type(8)));
typedef f16 f16x4 __attribute__((ext_vector_type(4)));
typedef float f32x4 __attribute__((ext_vector_type(4)));
typedef unsigned long long u64;
typedef unsigned u32;

// ---------------------------------------------------------------------------
// XCD-aware grid barrier, slot-arrival version (zeroed by hipMemsetAsync
// before each launch). Arrival = one uncontended store per block; master
// block polls all slots in parallel (256 thr x 4 slots). Leaders (first
// arriver per XCD at rendezvous) do ONE wbl2 + ONE L2-inv per barrier;
// everyone else only invalidates L1.
// ---------------------------------------------------------------------------
struct GBar {
    u32 arr[GRID_BLKS];  // per-block arrival generation
    u32 total[8][16];    // blocks per XCD (rendezvous)
    u32 pre[16];         // master: all-arrived flag (gen)
    u32 root[16];        // leader arrival count (cumulative)
    u32 flag[16];        // global release flag (gen)
    u32 done[8][16];     // per-XCD post-invalidate handshake (gen)
};

__device__ __forceinline__ void gb_rendezvous(GBar* g, int& myxcd,
                                              bool& leader, int& nact) {
    __shared__ int s_x, s_l, s_n;
    if (threadIdx.x == 0) {
        u32 xr;
        asm volatile("s_getreg_b32 %0, hwreg(HW_REG_XCC_ID)" : "=s"(xr));
        int x = (int)(xr & 7u);
        u32 prev = __hip_atomic_fetch_add(&g->total[x][0], 1u,
                                          __ATOMIC_RELAXED, AGS);
        for (;;) {  // wait for all blocks to register (read-only poll)
            u32 s = 0;
            for (int i = 0; i < 8; ++i)
                s += __hip_atomic_load(&g->total[i][0], __ATOMIC_RELAXED, AGS);
            if (s == GRID_BLKS) break;
            __builtin_amdgcn_s_sleep(1);
        }
        int n = 0;
        for (int i = 0; i < 8; ++i)
            n += (__hip_atomic_load(&g->total[i][0], __ATOMIC_RELAXED, AGS) !=
                  0);
        s_x = x;
        s_l = (prev == 0);
        s_n = n;
    }
    __syncthreads();
    myxcd = s_x;
    leader = (s_l != 0);
    nact = s_n;
}

__device__ __forceinline__ void gbar(GBar* g, int B, int t, bool leader,
                                     int myxcd, int nact, u32 gen) {
    __syncthreads();  // drain this block's stores to its L2 (vmcnt 0)
    if (t == 0) __hip_atomic_store(&g->arr[B], gen, __ATOMIC_RELAXED, AGS);
    if (B == 0) {  // master: parallel poll of all arrival slots
        __shared__ int sready;
        for (;;) {
            if (t == 0) sready = 1;
            __syncthreads();
            bool mine = true;
#pragma unroll
            for (int k2 = 0; k2 < 4; ++k2)
                mine &= (__hip_atomic_load(&g->arr[t * 4 + k2],
                                           __ATOMIC_RELAXED, AGS) >= gen);
            if (!mine) sready = 0;
            __syncthreads();
            if (sready) break;
            __builtin_amdgcn_s_sleep(1);
        }
        if (t == 0) __hip_atomic_store(&g->pre[0], gen, __ATOMIC_RELAXED, AGS);
    }
    if (t == 0) {
        if (leader) {
            while (__hip_atomic_load(&g->pre[0], __ATOMIC_RELAXED, AGS) < gen)
                __builtin_amdgcn_s_sleep(1);
            __builtin_amdgcn_fence(__ATOMIC_RELEASE, "agent");  // wbl2 (local)
            u32 r = __hip_atomic_fetch_add(&g->root[0], 1u, __ATOMIC_RELAXED,
                                           AGS);
            if (r == gen * (u32)nact - 1u) {  // global closer
                __hip_atomic_store(&g->flag[0], gen, __ATOMIC_RELEASE, AGS);
            } else {
                while (__hip_atomic_load(&g->flag[0], __ATOMIC_RELAXED, AGS) <
                       gen)
                    __builtin_amdgcn_s_sleep(1);
            }
            __builtin_amdgcn_fence(__ATOMIC_ACQUIRE, "agent");  // inv L2
            asm volatile("buffer_inv sc0" ::: "memory");
            __hip_atomic_store(&g->done[myxcd][0], gen, __ATOMIC_RELAXED, AGS);
        } else {
            while (__hip_atomic_load(&g->done[myxcd][0], __ATOMIC_RELAXED,
                                     AGS) < gen)
                __builtin_amdgcn_s_sleep(1);
            asm volatile("buffer_inv sc0" ::: "memory");  // L1-only inv
        }
    }
    __syncthreads();
}

// Shared-memory layout for attention phases.
template <int CGW, int NT>
struct AttnSmem {
    float Ls[4][NT][64];
    float As[4][64][NT * CGW * 4];
    f16 T[NT][16 * (CGW * 16 + 8)];
};
constexpr int SMEM_MEGA = sizeof(AttnSmem<2, 2>) > sizeof(AttnSmem<4, 1>)
                              ? (int)sizeof(AttnSmem<2, 2>)
                              : (int)sizeof(AttnSmem<4, 1>);  // 20992

// ---------------------------------------------------------------------------
// Prep body (virtual block B in [0,1024)): zero s-bufs; B<768: adj->maskT;
// 768..895: pack x into A-frags; 896..1023: weights -> B-frag WTF.
// ---------------------------------------------------------------------------
__device__ __forceinline__ void prep_body(
    int B, int t, const int* __restrict__ adj, const float* __restrict__ x,
    const float* __restrict__ W_heads, const float* __restrict__ W_out,
    u32* __restrict__ maskT, f16* __restrict__ Af, f16* __restrict__ WTF,
    float* __restrict__ sbuf) {
    int g = B * 256 + t;
    if (g < 221184) sbuf[g] = 0.f;  // 3 * (2*SH + 2*SO)

    if (B < 768) {
        for (int idx = g; idx < Bc * Nn * Nn; idx += 768 * 256) {
            u64 bl = __ballot(adj[idx] != 0);
            int lane = t & 63;
            int i = (idx >> 11) & 2047;
            int b = idx >> 22;
            int c32 = ((idx & 2047) & ~63) >> 5;
            if (lane == 0)
                maskT[((size_t)b * 64 + c32) * 2048 + i] = (u32)bl;
            else if (lane == 1)
                maskT[((size_t)b * 64 + c32 + 1) * 2048 + i] = (u32)(bl >> 32);
        }
    } else if (B < 896) {
        int w = t >> 6, lane = t & 63;
        int am = lane & 15, aq = lane >> 4;
#pragma unroll
        for (int it = 0; it < 4; ++it) {
            int slot = (B - 768) * 4 + w + it * 512;
            int mt = slot >> 3, c = slot & 7;
            const float* ap = x + ((size_t)mt * 16 + am) * Ff + c * 32 + aq * 8;
            f32x4 v0 = *(const f32x4*)ap;
            f32x4 v1 = *(const f32x4*)(ap + 4);
            f16x8 o;
#pragma unroll
            for (int i = 0; i < 4; ++i) { o[i] = (f16)v0[i]; o[4 + i] = (f16)v1[i]; }
            *(f16x8*)&Af[(size_t)slot * 512 + lane * 8] = o;
        }
    } else {
#pragma unroll
        for (int it = 0; it < 3; ++it) {
            int unit = (B - 896) * 3 + it;  // 0..383
            int y = unit >> 6, bx = unit & 63;
            int ll = y >> 1, st = y & 1;
            int col = bx * 4 + (t >> 6);
            int k0 = (t & 63) * 4;
            const float* src;
            int stride;
            if (st == 0) {
                src = W_heads + (((size_t)ll * Hh + (col >> 5)) * Ff) * Oo + (col & 31);
                stride = Oo;
            } else {
                src = W_out + (size_t)ll * Ff * Ff + col;
                stride = Ff;
            }
            f16x4 v;
#pragma unroll
            for (int i = 0; i < 4; ++i) v[i] = (f16)src[(size_t)(k0 + i) * stride];
            int cg = col >> 4, am = col & 15;
            int c = k0 >> 5, aq = (k0 >> 3) & 3, i0 = k0 & 7;
            *(f16x4*)&WTF[(((size_t)y * 16 + cg) * 8 + c) * 512 +
                          (aq * 16 + am) * 8 + i0] = v;
        }
    }
}

// ---------------------------------------------------------------------------
// Frag GEMM body: wave = 16 rows x 32 cols (2 cg), FULL-PRELOAD (8 A + 16 B
// frags). Virtual grid (64, 8). Epilogue: 2 WhFrag writes + s1/s2 (s2
// pre-scaled by LOG2E). Head (G=8): plain store; out (G=1): atomicAdd.
// ---------------------------------------------------------------------------
__device__ __forceinline__ void gemm_body(
    int bx, int by, int t, const f16* __restrict__ Af,
    const f16* __restrict__ WTF, const float* __restrict__ pa,
    f16* __restrict__ WhFrag, float* __restrict__ s1, float* __restrict__ s2,
    int G, int Ofull, int oshift) {
    int w = t >> 6, lane = t & 63;
    int am = lane & 15, aq = lane >> 4;
    int mt = bx * 4 + w;
    int colb = by * 32;

    const f16* ap = Af + (size_t)(mt * 8) * 512 + lane * 8;
    const f16* bp0 = WTF + (size_t)((colb >> 4) * 8) * 512 + lane * 8;
    const f16* bp1 = bp0 + 8 * 512;

    f16x8 av[8], bv0[8], bv1[8];
#pragma unroll
    for (int c = 0; c < 8; ++c) {
        av[c] = *(const f16x8*)(ap + c * 512);
        bv0[c] = *(const f16x8*)(bp0 + c * 512);
        bv1[c] = *(const f16x8*)(bp1 + c * 512);
    }
    f32x4 acc0 = {0.f, 0.f, 0.f, 0.f}, acc1 = acc0;
#pragma unroll
    for (int c = 0; c < 8; ++c) {
        acc0 = __builtin_amdgcn_mfma_f32_16x16x32_f16(av[c], bv0[c], acc0, 0, 0, 0);
        acc1 = __builtin_amdgcn_mfma_f32_16x16x32_f16(av[c], bv1[c], acc1, 0, 0, 0);
    }

    int m0 = mt * 16;
    int b = m0 >> 11;
    int nn0 = (m0 & 2047) + aq * 4;
    int cO = (m0 & 2047) >> 5;
    int aq_p = ((mt & 1) << 1) | (aq >> 1);
    int i0p = (aq & 1) << 2;
    int g = colb >> oshift;  // 32 cols within one g (head: colb mult of 32)
    size_t bg = (size_t)b * G + g;
    int cg = (colb & (Ofull - 1)) >> 4;

    f16x4 c40, c41;
#pragma unroll
    for (int e = 0; e < 4; ++e) { c40[e] = (f16)acc0[e]; c41[e] = (f16)acc1[e]; }
    *(f16x4*)&WhFrag[(((bg * (Ofull >> 4) + cg) * 64 + cO) * 512) +
                     (aq_p * 16 + am) * 8 + i0p] = c40;
    *(f16x4*)&WhFrag[(((bg * (Ofull >> 4) + cg + 1) * 64 + cO) * 512) +
                     (aq_p * 16 + am) * 8 + i0p] = c41;

    int o0 = (colb & (Ofull - 1)) + am;
    const float* a1p = pa + 2 * (size_t)g * Ofull;
    float a10 = a1p[o0], a11 = a1p[o0 + 16];
    float a20 = a1p[Ofull + o0], a21 = a1p[Ofull + o0 + 16];
#pragma unroll
    for (int e = 0; e < 4; ++e) {
        float p1 = acc0[e] * a10 + acc1[e] * a11;
        float p2 = acc0[e] * a20 + acc1[e] * a21;
#pragma unroll
        for (int s = 1; s < 16; s <<= 1) {
            p1 += __shfl_xor(p1, s);
            p2 += __shfl_xor(p2, s);
        }
        if (am == 0) {
            size_t sidx = bg * Nn + nn0 + e;
            if (G == 1) {
                atomicAdd(&s1[sidx], p1);
                atomicAdd(&s2[sidx], p2 * LOG2E);
            } else {  // single writer per slot for head GEMM
                s1[sidx] = p1;
                s2[sidx] = p2 * LOG2E;
            }
        }
    }
}

// ---------------------------------------------------------------------------
// Attention body: 4 waves = 4 j-slices; each wave = NT row-tiles (NT*16
// rows) x CGW*16 cols, prefetch-2, e-in-registers.
// NT=2: proven 32-row layout (head mega + both fallbacks).
// NT=1: 16-row layout for the 1024-block mega out-attn; epilogue split
// across all 4 waves (wave w owns col-group i=w), barrier before readback.
// ---------------------------------------------------------------------------
template <int CGW, int NT, bool OUT, bool FINAL>
__device__ __forceinline__ void attn_body(
    int bx, int by, int bz, int t, char* smemraw,
    const f16* __restrict__ WhFrag, const float* __restrict__ s1,
    const float* __restrict__ s2, const u32* __restrict__ maskT,
    float* __restrict__ dst, f16* __restrict__ AfOut) {
    constexpr float C0 = -ESHIFT * LOG2E - BIGM;
    constexpr float C08 = (1.0f - ALPHA_LRELU) * C0;
    constexpr int NCG = OUT ? 16 : 2;
    constexpr int TSTR = CGW * 16 + 8;  // f16 LDS row stride, 16B-aligned
    AttnSmem<CGW, NT>& sm = *(AttnSmem<CGW, NT>*)smemraw;

    __syncthreads();  // smem reuse guard (body called repeatedly in mega)

    int w = t >> 6, lane = t & 63;
    int am = lane & 15, aq = lane >> 4;
    int js = w & 3;  // j-slice
    int i0 = bx * (16 * NT);
    int b = OUT ? bz : (bz >> 3);
    int cg0 = OUT ? by * CGW : 0;
    int dstcol = OUT ? cg0 * 16 : (bz & 7) * Oo;

    const f16* bp[CGW];
#pragma unroll
    for (int i = 0; i < CGW; ++i)
        bp[i] = WhFrag + ((size_t)bz * NCG + cg0 + i) * 64 * 512 + lane * 8;
    const float* s2p = s2 + (size_t)bz * Nn + aq * 8;
    float s1c0 = fmaf(s1[(size_t)bz * Nn + i0 + am], LOG2E, C0);
    float s1c1 = 0.f;
    if (NT == 2) s1c1 = fmaf(s1[(size_t)bz * Nn + i0 + 16 + am], LOG2E, C0);
    const u32* mtp0 = maskT + (size_t)b * 64 * 2048 + i0 + am;
    const u32* mtp1 = mtp0 + 16;

    f32x4 acc[NT][CGW] = {};
    float lacc0 = 0.f, lacc1 = 0.f;

    int cbeg = js * 16, cend = cbeg + 16;  // this wave's j-slice (16 chunks)

    f16x8 xb[CGW], yb[CGW];
    f32x4 xv0, xv1, yv0, yv1;
    u32 xm0, xm1, ym0, ym1;
    auto ld = [&](int c, f16x8 (&bb)[CGW], f32x4& v0, f32x4& v1,
                  u32& m0, u32& m1) {
#pragma unroll
        for (int i = 0; i < CGW; ++i) bb[i] = *(const f16x8*)(bp[i] + c * 512);
        v0 = *(const f32x4*)(s2p + c * 32);
        v1 = *(const f32x4*)(s2p + c * 32 + 4);
        m0 = mtp0[c * 2048];
        if (NT == 2) m1 = mtp1[c * 2048];
    };
    auto comp = [&](f16x8 (&bb)[CGW], f32x4 v0, f32x4 v1, u32 m0, u32 m1) {
        u32 bits0 = (m0 >> (aq * 8)) & 0xffu;
        u32 bits1 = NT == 2 ? (m1 >> (aq * 8)) & 0xffu : 0u;
        f16x8 af0, af1;
#pragma unroll
        for (int k = 0; k < 8; ++k) {
            float sv = (k < 4 ? v0[k] : v1[k - 4]);  // already * LOG2E
            float u0 = s1c0 + sv;
            float lr0 = fmaxf(u0, fmaf(ALPHA_LRELU, u0, C08));
            float bf0 = (float)((bits0 >> k) & 1u);
            float p0 = EXP2(fmaf(bf0, BIGM, lr0));
            lacc0 += p0;
            af0[k] = (f16)p0;
            if (NT == 2) {
                float u1 = s1c1 + sv;
                float lr1 = fmaxf(u1, fmaf(ALPHA_LRELU, u1, C08));
                float bf1 = (float)((bits1 >> k) & 1u);
                float p1 = EXP2(fmaf(bf1, BIGM, lr1));
                lacc1 += p1;
                af1[k] = (f16)p1;
            }
        }
#pragma unroll
        for (int i = 0; i < CGW; ++i) {
            acc[0][i] = __builtin_amdgcn_mfma_f32_16x16x32_f16(af0, bb[i], acc[0][i], 0, 0, 0);
            if (NT == 2)
                acc[NT - 1][i] = __builtin_amdgcn_mfma_f32_16x16x32_f16(af1, bb[i], acc[NT - 1][i], 0, 0, 0);
        }
    };

    ld(cbeg, xb, xv0, xv1, xm0, xm1);
    ld(cbeg + 1, yb, yv0, yv1, ym0, ym1);
    for (int c = cbeg; c < cend; c += 2) {
        comp(xb, xv0, xv1, xm0, xm1);
        ld(c + 2 < cend ? c + 2 : cbeg, xb, xv0, xv1, xm0, xm1);
        comp(yb, yv0, yv1, ym0, ym1);
        ld(c + 3 < cend ? c + 3 : cbeg, yb, yv0, yv1, ym0, ym1);
    }

    // intra-wave l: sum over aq groups -> lane holds l_slice[am] per tile
    lacc0 += __shfl_xor(lacc0, 16);
    lacc0 += __shfl_xor(lacc0, 32);
    if (NT == 2) {
        lacc1 += __shfl_xor(lacc1, 16);
        lacc1 += __shfl_xor(lacc1, 32);
    }

    sm.Ls[w][0][lane] = lacc0;
    if (NT == 2) sm.Ls[w][NT - 1][lane] = lacc1;
#pragma unroll
    for (int tt = 0; tt < NT; ++tt)
#pragma unroll
        for (int i = 0; i < CGW; ++i)
#pragma unroll
            for (int e = 0; e < 4; ++e)
                sm.As[w][lane][tt * CGW * 4 + i * 4 + e] = acc[tt][i][e];
    __syncthreads();

    if constexpr (NT == 2) {
        if (w < 2) {  // wave tt finishes row tile tt for this block's cols
            int tt = w;
            float lt = sm.Ls[0][tt][lane] + sm.Ls[1][tt][lane] +
                       sm.Ls[2][tt][lane] + sm.Ls[3][tt][lane];
            float rli[4];
#pragma unroll
            for (int e = 0; e < 4; ++e) rli[e] = 1.0f / __shfl(lt, aq * 4 + e);
            f16* Tw = sm.T[tt];
#pragma unroll
            for (int i = 0; i < CGW; ++i) {
                f32x4 a;
#pragma unroll
                for (int e = 0; e < 4; ++e)
                    a[e] = sm.As[0][lane][tt * CGW * 4 + i * 4 + e] +
                           sm.As[1][lane][tt * CGW * 4 + i * 4 + e] +
                           sm.As[2][lane][tt * CGW * 4 + i * 4 + e] +
                           sm.As[3][lane][tt * CGW * 4 + i * 4 + e];
#pragma unroll
                for (int e = 0; e < 4; ++e) {
                    int r = aq * 4 + e;  // C/D: col=am, row=aq*4+e
                    float v = a[e] * rli[e];
                    v = v > 0.f ? v : __expf(v) - 1.f;
                    if (OUT) v = v > 0.f ? v : __expf(v) - 1.f;
                    if (FINAL) {
                        dst[((size_t)b * Nn + i0 + tt * 16 + r) * Ff + dstcol +
                            i * 16 + am] = v;
                    } else {
                        Tw[r * TSTR + i * 16 + am] = (f16)v;
                    }
                }
            }
            if (!FINAL) {
                // in-wave read-back in A-frag order (same wave's data)
                int mt = (b * Nn + i0 + tt * 16) >> 4;  // GLOBAL row tile
#pragma unroll
                for (int s = 0; s < CGW / 2; ++s) {
                    f16x8 o = *(const f16x8*)&Tw[am * TSTR + s * 32 + aq * 8];
                    int c = (dstcol >> 5) + s;
                    *(f16x8*)&AfOut[(size_t)(mt * 8 + c) * 512 + lane * 8] = o;
                }
            }
        }
    } else {  // NT == 1: single 16-row tile, epilogue split across 4 waves
        float lt = sm.Ls[0][0][lane] + sm.Ls[1][0][lane] + sm.Ls[2][0][lane] +
                   sm.Ls[3][0][lane];
        float rli[4];
#pragma unroll
        for (int e = 0; e < 4; ++e) rli[e] = 1.0f / __shfl(lt, aq * 4 + e);
        if (w < CGW) {
            int i = w;  // this wave owns col-group i
            f32x4 a;
#pragma unroll
            for (int e = 0; e < 4; ++e)
                a[e] = sm.As[0][lane][i * 4 + e] + sm.As[1][lane][i * 4 + e] +
                       sm.As[2][lane][i * 4 + e] + sm.As[3][lane][i * 4 + e];
#pragma unroll
            for (int e = 0; e < 4; ++e) {
                int r = aq * 4 + e;  // C/D: col=am, row=aq*4+e
                float v = a[e] * rli[e];
                v = v > 0.f ? v : __expf(v) - 1.f;
                if (OUT) v = v > 0.f ? v : __expf(v) - 1.f;
                if (FINAL) {
                    dst[((size_t)b * Nn + i0 + r) * Ff + dstcol + i * 16 +
                        am] = v;
                } else {
                    sm.T[0][r * TSTR + i * 16 + am] = (f16)v;
                }
            }
        }
        if constexpr (!FINAL) {
            __syncthreads();  // T written by waves 0..CGW-1
            if (w < CGW / 2) {
                int s = w;
                f16x8 o = *(const f16x8*)&sm.T[0][am * TSTR + s * 32 + aq * 8];
                int mt = (b * Nn + i0) >> 4;
                int c = (dstcol >> 5) + s;
                *(f16x8*)&AfOut[(size_t)(mt * 8 + c) * 512 + lane * 8] = o;
            }
        }
    }
}

// ---------------------------------------------------------------------------
// Persistent mega-kernel: 1024 blocks x 256 thr = 4 blocks/CU co-resident
// (LDS 21 KB, launch_bounds(256,4) caps VGPR at 128) -> 16 waves/CU, 2x the
// R3 occupancy. 12 slot-arrival XCD barriers replace kernel boundaries.
// GEMM phases have 2048 wave-tasks -> blocks >=512 idle through them (~2us).
// ---------------------------------------------------------------------------
__global__ __launch_bounds__(256, 4) void mega_kernel(
    const int* __restrict__ adj, const float* __restrict__ x,
    const float* __restrict__ W_heads, const float* __restrict__ a_heads,
    const float* __restrict__ W_out, const float* __restrict__ a_out,
    float* __restrict__ out, u32* __restrict__ maskT, f16* __restrict__ Af_a,
    f16* __restrict__ Af_b, f16* __restrict__ WhFrag, f16* __restrict__ WTF,
    float* __restrict__ sbuf, GBar* __restrict__ gb) {
    __shared__ __align__(16) char smem[SMEM_MEGA];
    const int B = blockIdx.x;
    const int t = threadIdx.x;

    int myxcd = 0, nact = 0;
    bool leader = false;
    gb_rendezvous(gb, myxcd, leader, nact);
    u32 gen = 0;

    prep_body(B, t, adj, x, W_heads, W_out, maskT, Af_a, WTF, sbuf);
    gbar(gb, B, t, leader, myxcd, nact, ++gen);

    const size_t SH = (size_t)Bc * Hh * Nn;  // 32768
    const size_t SO = (size_t)Bc * Nn;       // 4096
    const size_t SL = 2 * SH + 2 * SO;

    for (int l = 0; l < 3; ++l) {
        float* s1h = sbuf + l * SL;
        float* s2h = s1h + SH;
        float* s1o = s2h + SH;
        float* s2o = s1o + SO;

        // ---- head GAT: G=8, O=32; virtual grid (64,8) on blocks <512 ----
        if (B < 512)
            gemm_body(B & 63, B >> 6, t, Af_a, WTF + (size_t)(2 * l) * Ff * Ff,
                      a_heads + (size_t)l * Hh * 2 * Oo, WhFrag, s1h, s2h, Hh,
                      Oo, 5);
        gbar(gb, B, t, leader, myxcd, nact, ++gen);
        // head attn: virtual grid (64,1,16) 1:1
        attn_body<2, 2, false, false>(B & 63, 0, B >> 6, t, smem, WhFrag, s1h,
                                      s2h, maskT, nullptr, Af_b);
        gbar(gb, B, t, leader, myxcd, nact, ++gen);

        // ---- out GAT: G=1, O=F=256; virtual grid (64,8) on blocks <512 ----
        if (B < 512)
            gemm_body(B & 63, B >> 6, t, Af_b,
                      WTF + (size_t)(2 * l + 1) * Ff * Ff,
                      a_out + (size_t)l * 2 * Ff, WhFrag, s1o, s2o, 1, Ff, 8);
        gbar(gb, B, t, leader, myxcd, nact, ++gen);
        // out attn: virtual grid (128,4,2), NT=1 (16-row tiles)
        if (l < 2) {
            attn_body<4, 1, true, false>(B & 127, (B >> 7) & 3, B >> 9, t,
                                         smem, WhFrag, s1o, s2o, maskT, out,
                                         Af_a);
            gbar(gb, B, t, leader, myxcd, nact, ++gen);
        } else {
            attn_body<4, 1, true, true>(B & 127, (B >> 7) & 3, B >> 9, t, smem,
                                        WhFrag, s1o, s2o, maskT, out, Af_a);
        }
    }
}

// ---------------------------------------------------------------------------
// Fallback wrappers (13-launch path), sharing the same bodies (NT=2 proven).
// ---------------------------------------------------------------------------
__global__ __launch_bounds__(256) void prep_kernel(
    const int* __restrict__ adj, const float* __restrict__ x,
    const float* __restrict__ W_heads, const float* __restrict__ W_out,
    u32* __restrict__ maskT, f16* __restrict__ Af, f16* __restrict__ WTF,
    float* __restrict__ sbuf) {
    prep_body(blockIdx.x, threadIdx.x, adj, x, W_heads, W_out, maskT, Af, WTF,
              sbuf);
}

__global__ __launch_bounds__(256) void gemm_wave(
    const f16* __restrict__ Af, const f16* __restrict__ WTF,
    const float* __restrict__ pa, f16* __restrict__ WhFrag,
    float* __restrict__ s1, float* __restrict__ s2, int G, int Ofull,
    int oshift) {
    gemm_body(blockIdx.x, blockIdx.y, threadIdx.x, Af, WTF, pa, WhFrag, s1, s2,
              G, Ofull, oshift);
}

template <int CGW, bool OUT, bool FINAL>
__global__ __launch_bounds__(256) void attn_kernel(
    const f16* __restrict__ WhFrag, const float* __restrict__ s1,
    const float* __restrict__ s2, const u32* __restrict__ maskT,
    float* __restrict__ dst, f16* __restrict__ AfOut) {
    __shared__ __align__(16) char smem[sizeof(AttnSmem<CGW, 2>)];
    attn_body<CGW, 2, OUT, FINAL>(blockIdx.x, blockIdx.y, blockIdx.z,
                                  threadIdx.x, smem, WhFrag, s1, s2, maskT,
                                  dst, AfOut);
}

// ---------------------------------------------------------------------------
extern "C" void kernel_launch(void* const* d_in, const int* in_sizes, int n_in,
                              void* d_out, int out_size, void* d_ws, size_t ws_size,
                              hipStream_t stream) {
    const float* x = (const float*)d_in[0];
    const int* adj = (const int*)d_in[1];
    const float* W_heads = (const float*)d_in[2];
    const float* a_heads = (const float*)d_in[3];
    const float* W_out = (const float*)d_in[4];
    const float* a_out = (const float*)d_in[5];
    float* out = (float*)d_out;

    float* ws = (float*)d_ws;
    const size_t M = (size_t)Bc * Nn * Ff;      // 1,048,576
    f16* Af_a = (f16*)ws;                       // M f16
    f16* Af_b = (f16*)(ws + M / 2);             // M f16
    f16* WhFrag = (f16*)(ws + M);               // M f16
    u32* maskT = (u32*)(ws + 3 * M / 2);        // 1 MB
    f16* WTF = (f16*)(ws + 3 * M / 2 + M / 4);  // 6*F*F f16 = 196608 floats
    float* sbuf = ws + 3 * M / 2 + M / 4 + 196608;
    GBar* gb = (GBar*)(ws + 3 * M);             // 12 MB offset, well clear
    const size_t SH = (size_t)Bc * Hh * Nn;     // 32768
    const size_t SO = (size_t)Bc * Nn;          // 4096
    const size_t SL = 2 * SH + 2 * SO;

    // ---- preferred: single persistent kernel with custom grid barrier ----
    {
        hipMemsetAsync(gb, 0, sizeof(GBar), stream);
        const int* a_adj = adj;
        const float* a_x = x;
        const float* a_Wh = W_heads;
        const float* a_ah = a_heads;
        const float* a_Wo = W_out;
        const float* a_ao = a_out;
        float* a_out_p = out;
        u32* a_maskT = maskT;
        f16* a_Afa = Af_a;
        f16* a_Afb = Af_b;
        f16* a_Whf = WhFrag;
        f16* a_WTF = WTF;
        float* a_sbuf = sbuf;
        GBar* a_gb = gb;
        void* args[] = {&a_adj,   &a_x,     &a_Wh,    &a_ah,  &a_Wo,
                        &a_ao,    &a_out_p, &a_maskT, &a_Afa, &a_Afb,
                        &a_Whf,   &a_WTF,   &a_sbuf,  &a_gb};
        hipError_t err = hipLaunchCooperativeKernel(
            (const void*)mega_kernel, dim3(GRID_BLKS), dim3(256), args, 0,
            stream);
        if (err == hipSuccess) return;
        (void)hipGetLastError();  // clear error state, fall through
    }

    // ---- fallback: original 13-launch pipeline ----
    prep_kernel<<<1024, 256, 0, stream>>>(adj, x, W_heads, W_out, maskT, Af_a,
                                          WTF, sbuf);
    for (int l = 0; l < 3; ++l) {
        float* s1h = sbuf + l * SL;
        float* s2h = s1h + SH;
        float* s1o = s2h + SH;
        float* s2o = s1o + SO;

        gemm_wave<<<dim3((Bc * Nn) / 64, Ff / 32), 256, 0, stream>>>(
            Af_a, WTF + (size_t)(2 * l) * Ff * Ff,
            a_heads + (size_t)l * Hh * 2 * Oo, WhFrag, s1h, s2h, Hh, Oo, 5);
        attn_kernel<2, false, false><<<dim3(Nn / 32, 1, Bc * Hh), 256, 0,
                                       stream>>>(WhFrag, s1h, s2h, maskT,
                                                 nullptr, Af_b);

        gemm_wave<<<dim3((Bc * Nn) / 64, Ff / 32), 256, 0, stream>>>(
            Af_b, WTF + (size_t)(2 * l + 1) * Ff * Ff,
            a_out + (size_t)l * 2 * Ff, WhFrag, s1o, s2o, 1, Ff, 8);
        if (l == 2) {
            attn_kernel<4, true, true><<<dim3(Nn / 32, Ff / 64, Bc), 256, 0,
                                         stream>>>(WhFrag, s1o, s2o, maskT, out,
                                                   nullptr);
        } else {
            attn_kernel<4, true, false><<<dim3(Nn / 32, Ff / 64, Bc), 256, 0,
                                          stream>>>(WhFrag, s1o, s2o, maskT,
                                                    nullptr, Af_a);
        }
    }
}

// Round 7
// 279.972 us; speedup vs baseline: 1.3026x; 1.3026x over previous
//
#include <hip/hip_runtime.h>
#include <math.h>

#if __has_builtin(__builtin_amdgcn_exp2f)
#define EXP2(x) __builtin_amdgcn_exp2f(x)
#else
#define EXP2(x) exp2f(x)
#endif

#define ALPHA_LRELU 0.2f
#define LOG2E 1.4426950408889634f
#define ESHIFT 6.0f

constexpr int Bc = 2, Nn = 2048, Ff = 256, Hh = 8, Oo = 32;

typedef _Float16 f16;
typedef f16 f16x8 __attribute__((ext_vector_type(8)));
typedef f16 f16x4 __attribute__((ext_vector_type(4)));
typedef float f32x4 __attribute__((ext_vector_type(4)));
typedef unsigned long long u64;
typedef unsigned u32;

// ---------------------------------------------------------------------------
// Fused prep: zero s-bufs; B<768: adj->maskT; 768..895: pack x into A-frags;
// 896..1023: weights -> B-frag WTF.  (R1-measured, unchanged.)
// ---------------------------------------------------------------------------
__global__ __launch_bounds__(256) void prep_kernel(
    const int* __restrict__ adj, const float* __restrict__ x,
    const float* __restrict__ W_heads, const float* __restrict__ W_out,
    u32* __restrict__ maskT, f16* __restrict__ Af, f16* __restrict__ WTF,
    float* __restrict__ sbuf) {
    const int B = blockIdx.x;
    const int t = threadIdx.x;
    int g = B * 256 + t;
    if (g < 221184) sbuf[g] = 0.f;  // 3 * (2*SH + 2*SO)

    if (B < 768) {
        for (int idx = g; idx < Bc * Nn * Nn; idx += 768 * 256) {
            u64 bl = __ballot(adj[idx] != 0);
            int lane = t & 63;
            int i = (idx >> 11) & 2047;
            int b = idx >> 22;
            int c32 = ((idx & 2047) & ~63) >> 5;
            if (lane == 0)
                maskT[((size_t)b * 64 + c32) * 2048 + i] = (u32)bl;
            else if (lane == 1)
                maskT[((size_t)b * 64 + c32 + 1) * 2048 + i] = (u32)(bl >> 32);
        }
    } else if (B < 896) {
        int w = t >> 6, lane = t & 63;
        int am = lane & 15, aq = lane >> 4;
#pragma unroll
        for (int it = 0; it < 4; ++it) {
            int slot = (B - 768) * 4 + w + it * 512;
            int mt = slot >> 3, c = slot & 7;
            const float* ap = x + ((size_t)mt * 16 + am) * Ff + c * 32 + aq * 8;
            f32x4 v0 = *(const f32x4*)ap;
            f32x4 v1 = *(const f32x4*)(ap + 4);
            f16x8 o;
#pragma unroll
            for (int i = 0; i < 4; ++i) { o[i] = (f16)v0[i]; o[4 + i] = (f16)v1[i]; }
            *(f16x8*)&Af[(size_t)slot * 512 + lane * 8] = o;
        }
    } else {
#pragma unroll
        for (int it = 0; it < 3; ++it) {
            int unit = (B - 896) * 3 + it;  // 0..383
            int y = unit >> 6, bx = unit & 63;
            int ll = y >> 1, st = y & 1;
            int col = bx * 4 + (t >> 6);
            int k0 = (t & 63) * 4;
            const float* src;
            int stride;
            if (st == 0) {
                src = W_heads + (((size_t)ll * Hh + (col >> 5)) * Ff) * Oo + (col & 31);
                stride = Oo;
            } else {
                src = W_out + (size_t)ll * Ff * Ff + col;
                stride = Ff;
            }
            f16x4 v;
#pragma unroll
            for (int i = 0; i < 4; ++i) v[i] = (f16)src[(size_t)(k0 + i) * stride];
            int cg = col >> 4, am = col & 15;
            int c = k0 >> 5, aq = (k0 >> 3) & 3, i0 = k0 & 7;
            *(f16x4*)&WTF[(((size_t)y * 16 + cg) * 8 + c) * 512 +
                          (aq * 16 + am) * 8 + i0] = v;
        }
    }
}

// ---------------------------------------------------------------------------
// Frag GEMM: wave = 16 rows x 32 cols (2 cg), FULL-PRELOAD. Grid (64,8).
// Epilogue: 2 WhFrag writes + s1/s2. s2 pre-scaled by LOG2E (saves a mul/k
// in attn). Head (G=8): single writer per s-slot -> plain store; out (G=1):
// 8 col blocks contend -> atomicAdd.  (Proven in R3/R5 passes.)
// ---------------------------------------------------------------------------
__global__ __launch_bounds__(256) void gemm_wave(
    const f16* __restrict__ Af, const f16* __restrict__ WTF,
    const float* __restrict__ pa, f16* __restrict__ WhFrag,
    float* __restrict__ s1, float* __restrict__ s2,
    int G, int Ofull, int oshift) {
    int t = threadIdx.x;
    int w = t >> 6, lane = t & 63;
    int am = lane & 15, aq = lane >> 4;
    int mt = blockIdx.x * 4 + w;
    int colb = blockIdx.y * 32;

    const f16* ap = Af + (size_t)(mt * 8) * 512 + lane * 8;
    const f16* bp0 = WTF + (size_t)((colb >> 4) * 8) * 512 + lane * 8;
    const f16* bp1 = bp0 + 8 * 512;

    f16x8 av[8], bv0[8], bv1[8];
#pragma unroll
    for (int c = 0; c < 8; ++c) {
        av[c] = *(const f16x8*)(ap + c * 512);
        bv0[c] = *(const f16x8*)(bp0 + c * 512);
        bv1[c] = *(const f16x8*)(bp1 + c * 512);
    }
    f32x4 acc0 = {0.f, 0.f, 0.f, 0.f}, acc1 = acc0;
#pragma unroll
    for (int c = 0; c < 8; ++c) {
        acc0 = __builtin_amdgcn_mfma_f32_16x16x32_f16(av[c], bv0[c], acc0, 0, 0, 0);
        acc1 = __builtin_amdgcn_mfma_f32_16x16x32_f16(av[c], bv1[c], acc1, 0, 0, 0);
    }

    int m0 = mt * 16;
    int b = m0 >> 11;
    int nn0 = (m0 & 2047) + aq * 4;
    int cO = (m0 & 2047) >> 5;
    int aq_p = ((mt & 1) << 1) | (aq >> 1);
    int i0p = (aq & 1) << 2;
    int g = colb >> oshift;  // 32 cols within one g (head: colb mult of 32)
    size_t bg = (size_t)b * G + g;
    int cg = (colb & (Ofull - 1)) >> 4;

    f16x4 c40, c41;
#pragma unroll
    for (int e = 0; e < 4; ++e) { c40[e] = (f16)acc0[e]; c41[e] = (f16)acc1[e]; }
    *(f16x4*)&WhFrag[(((bg * (Ofull >> 4) + cg) * 64 + cO) * 512) +
                     (aq_p * 16 + am) * 8 + i0p] = c40;
    *(f16x4*)&WhFrag[(((bg * (Ofull >> 4) + cg + 1) * 64 + cO) * 512) +
                     (aq_p * 16 + am) * 8 + i0p] = c41;

    int o0 = (colb & (Ofull - 1)) + am;
    const float* a1p = pa + 2 * (size_t)g * Ofull;
    float a10 = a1p[o0], a11 = a1p[o0 + 16];
    float a20 = a1p[Ofull + o0], a21 = a1p[Ofull + o0 + 16];
#pragma unroll
    for (int e = 0; e < 4; ++e) {
        float p1 = acc0[e] * a10 + acc1[e] * a11;
        float p2 = acc0[e] * a20 + acc1[e] * a21;
#pragma unroll
        for (int s = 1; s < 16; s <<= 1) {
            p1 += __shfl_xor(p1, s);
            p2 += __shfl_xor(p2, s);
        }
        if (am == 0) {
            size_t sidx = bg * Nn + nn0 + e;
            if (G == 1) {
                atomicAdd(&s1[sidx], p1);
                atomicAdd(&s2[sidx], p2 * LOG2E);
            } else {  // single writer per slot for head GEMM
                s1[sidx] = p1;
                s2[sidx] = p2 * LOG2E;
            }
        }
    }
}

// ---------------------------------------------------------------------------
// Attention (R1-measured NW-wave structure): NW waves = (NW/4 col-halves) x
// (4 j-slices); each wave = 2 row-tiles (32 rows) x CGW*16 cols, prefetch-2,
// e-in-registers.  Head: NW=4, CGW=2, grid (64,1,16).  Out: NW=8, CGW=4,
// grid (64,2,2), 512 thr.
// R7 e-chain: (1) l via ones-MFMA (row-sums from the matrix pipe; deletes
// 32 adds/chunk + end shuffles; l sums the SAME f16-rounded p as PV);
// (2) post-exp AND-mask (exp2(lr) & (0-bit)) — no +-1024 round-trip.
// f32->f16 stays scalar casts (m240: hand-packed cvt_pk is slower).
// ---------------------------------------------------------------------------
template <int CGW, int NW, bool OUT, bool FINAL>
__global__ __launch_bounds__(NW * 64) void attn_kernel(
    const f16* __restrict__ WhFrag, const float* __restrict__ s1,
    const float* __restrict__ s2, const u32* __restrict__ maskT,
    float* __restrict__ dst, f16* __restrict__ AfOut) {
    constexpr float C0 = -ESHIFT * LOG2E;               // fixed softmax shift
    constexpr float C08 = (1.0f - ALPHA_LRELU) * C0;
    constexpr int NCG = OUT ? 16 : 2;
    constexpr int COLS = (NW / 4) * CGW * 16;  // block col coverage
    constexpr int TSTR = COLS + 8;             // f16 LDS row stride, 16B-aligned
    __shared__ float Ls[NW][2][64];
    __shared__ float As[NW][64][2 * CGW * 4];
    __shared__ f16 T[2][16 * TSTR];

    int t = threadIdx.x;
    int w = t >> 6, lane = t & 63;
    int am = lane & 15, aq = lane >> 4;
    int ch = w >> 2;   // col-half
    int js = w & 3;    // j-slice
    int i0 = blockIdx.x * 32;
    int bz = blockIdx.z;
    int b = OUT ? bz : (bz >> 3);
    int cg0 = OUT ? blockIdx.y * ((NW / 4) * CGW) + ch * CGW : 0;
    int dstcol = OUT ? cg0 * 16 : (bz & 7) * Oo;

    const f16* bp[CGW];
#pragma unroll
    for (int i = 0; i < CGW; ++i)
        bp[i] = WhFrag + ((size_t)bz * NCG + cg0 + i) * 64 * 512 + lane * 8;
    const float* s2p = s2 + (size_t)bz * Nn + aq * 8;  // s2 pre-scaled LOG2E
    float s1c0 = fmaf(s1[(size_t)bz * Nn + i0 + am], LOG2E, C0);
    float s1c1 = fmaf(s1[(size_t)bz * Nn + i0 + 16 + am], LOG2E, C0);
    const u32* mtp0 = maskT + (size_t)b * 64 * 2048 + i0 + am;
    const u32* mtp1 = mtp0 + 16;

    f32x4 acc[2][CGW] = {};
    f32x4 accL0 = {0.f, 0.f, 0.f, 0.f}, accL1 = accL0;  // l accumulators
    f16x8 ones;
#pragma unroll
    for (int i = 0; i < 8; ++i) ones[i] = (f16)1.0f;

    int cbeg = js * 16, cend = cbeg + 16;  // this wave's j-slice (16 chunks)

    f16x8 xb[CGW], yb[CGW];
    f32x4 xv0, xv1, yv0, yv1;
    u32 xm0, xm1, ym0, ym1;
    auto ld = [&](int c, f16x8 (&bb)[CGW], f32x4& v0, f32x4& v1,
                  u32& m0, u32& m1) {
#pragma unroll
        for (int i = 0; i < CGW; ++i) bb[i] = *(const f16x8*)(bp[i] + c * 512);
        v0 = *(const f32x4*)(s2p + c * 32);
        v1 = *(const f32x4*)(s2p + c * 32 + 4);
        m0 = mtp0[c * 2048];
        m1 = mtp1[c * 2048];
    };
    auto comp = [&](f16x8 (&bb)[CGW], f32x4 v0, f32x4 v1, u32 m0, u32 m1) {
        u32 bits0 = (m0 >> (aq * 8)) & 0xffu;
        u32 bits1 = (m1 >> (aq * 8)) & 0xffu;
        f16x8 af0, af1;
#pragma unroll
        for (int k = 0; k < 8; ++k) {
            float sv = (k < 4 ? v0[k] : v1[k - 4]);  // already * LOG2E
            float u0 = s1c0 + sv;
            float u1 = s1c1 + sv;
            float lr0 = fmaxf(u0, fmaf(ALPHA_LRELU, u0, C08));
            float lr1 = fmaxf(u1, fmaf(ALPHA_LRELU, u1, C08));
            // post-exp AND mask: bit=0 -> p = +0.0 exactly
            u32 z0 = 0u - ((bits0 >> k) & 1u);
            u32 z1 = 0u - ((bits1 >> k) & 1u);
            float p0 = __uint_as_float(__float_as_uint(EXP2(lr0)) & z0);
            float p1 = __uint_as_float(__float_as_uint(EXP2(lr1)) & z1);
            af0[k] = (f16)p0;
            af1[k] = (f16)p1;
        }
        // l via ones-MFMA: D[r][c] = sum_k P[r][k] (dup over cols)
        accL0 = __builtin_amdgcn_mfma_f32_16x16x32_f16(af0, ones, accL0, 0, 0, 0);
        accL1 = __builtin_amdgcn_mfma_f32_16x16x32_f16(af1, ones, accL1, 0, 0, 0);
#pragma unroll
        for (int i = 0; i < CGW; ++i) {
            acc[0][i] = __builtin_amdgcn_mfma_f32_16x16x32_f16(af0, bb[i], acc[0][i], 0, 0, 0);
            acc[1][i] = __builtin_amdgcn_mfma_f32_16x16x32_f16(af1, bb[i], acc[1][i], 0, 0, 0);
        }
    };

    ld(cbeg, xb, xv0, xv1, xm0, xm1);
    ld(cbeg + 1, yb, yv0, yv1, ym0, ym1);
    for (int c = cbeg; c < cend; c += 2) {
        comp(xb, xv0, xv1, xm0, xm1);
        ld(c + 2 < cend ? c + 2 : cbeg, xb, xv0, xv1, xm0, xm1);
        comp(yb, yv0, yv1, ym0, ym1);
        ld(c + 3 < cend ? c + 3 : cbeg, yb, yv0, yv1, ym0, ym1);
    }

    // l lives in accL: lane (am,aq) holds l_partial[row aq*4+e] (dup over am).
    // Lanes with am==0 publish rows 0..15 into Ls[w][tt][row].
    if (am == 0) {
#pragma unroll
        for (int e = 0; e < 4; ++e) {
            Ls[w][0][aq * 4 + e] = accL0[e];
            Ls[w][1][aq * 4 + e] = accL1[e];
        }
    }
#pragma unroll
    for (int tt = 0; tt < 2; ++tt)
#pragma unroll
        for (int i = 0; i < CGW; ++i)
#pragma unroll
            for (int e = 0; e < 4; ++e)
                As[w][lane][tt * CGW * 4 + i * 4 + e] = acc[tt][i][e];
    __syncthreads();

    if ((w & 3) < 2) {  // wave (ch, tt=js) finishes row tile tt for its cols
        int tt = w & 3;
        // lt meaningful for lane<16 (row index); shfl below sources 0..15 only
        float lt = Ls[ch * 4 + 0][tt][lane] + Ls[ch * 4 + 1][tt][lane] +
                   Ls[ch * 4 + 2][tt][lane] + Ls[ch * 4 + 3][tt][lane];
        float rli[4];
#pragma unroll
        for (int e = 0; e < 4; ++e) rli[e] = 1.0f / __shfl(lt, aq * 4 + e);
        f16* Tw = T[tt];
#pragma unroll
        for (int i = 0; i < CGW; ++i) {
            f32x4 a;
#pragma unroll
            for (int e = 0; e < 4; ++e)
                a[e] = As[ch * 4 + 0][lane][tt * CGW * 4 + i * 4 + e] +
                       As[ch * 4 + 1][lane][tt * CGW * 4 + i * 4 + e] +
                       As[ch * 4 + 2][lane][tt * CGW * 4 + i * 4 + e] +
                       As[ch * 4 + 3][lane][tt * CGW * 4 + i * 4 + e];
#pragma unroll
            for (int e = 0; e < 4; ++e) {
                int r = aq * 4 + e;             // C/D: col=am, row=aq*4+e
                float v = a[e] * rli[e];
                v = v > 0.f ? v : __expf(v) - 1.f;
                if (OUT) v = v > 0.f ? v : __expf(v) - 1.f;
                if (FINAL) {
                    dst[((size_t)b * Nn + i0 + tt * 16 + r) * Ff + dstcol +
                        i * 16 + am] = v;
                } else {
                    Tw[r * TSTR + ch * CGW * 16 + i * 16 + am] = (f16)v;
                }
            }
        }
        if (!FINAL) {
            // in-wave read-back in A-frag order (no barrier: same wave's data)
            int mt = (b * Nn + i0 + tt * 16) >> 4;  // GLOBAL row tile
#pragma unroll
            for (int s = 0; s < CGW / 2; ++s) {
                f16x8 o = *(const f16x8*)&Tw[am * TSTR + ch * CGW * 16 +
                                             s * 32 + aq * 8];
                int c = (dstcol >> 5) + s;
                *(f16x8*)&AfOut[(size_t)(mt * 8 + c) * 512 + lane * 8] = o;
            }
        }
    }
}

// ---------------------------------------------------------------------------
extern "C" void kernel_launch(void* const* d_in, const int* in_sizes, int n_in,
                              void* d_out, int out_size, void* d_ws, size_t ws_size,
                              hipStream_t stream) {
    const float* x = (const float*)d_in[0];
    const int* adj = (const int*)d_in[1];
    const float* W_heads = (const float*)d_in[2];
    const float* a_heads = (const float*)d_in[3];
    const float* W_out = (const float*)d_in[4];
    const float* a_out = (const float*)d_in[5];
    float* out = (float*)d_out;

    float* ws = (float*)d_ws;
    const size_t M = (size_t)Bc * Nn * Ff;        // 1,048,576
    f16* Af_a = (f16*)ws;                         // M f16
    f16* Af_b = (f16*)(ws + M / 2);               // M f16
    f16* WhFrag = (f16*)(ws + M);                 // M f16
    u32* maskT = (u32*)(ws + 3 * M / 2);          // 1 MB
    f16* WTF = (f16*)(ws + 3 * M / 2 + M / 4);    // 6*F*F f16 = 196608 floats
    float* sbuf = ws + 3 * M / 2 + M / 4 + 196608;
    const size_t SH = (size_t)Bc * Hh * Nn;       // 32768
    const size_t SO = (size_t)Bc * Nn;            // 4096
    const size_t SL = 2 * SH + 2 * SO;

    prep_kernel<<<1024, 256, 0, stream>>>(adj, x, W_heads, W_out,
                                          maskT, Af_a, WTF, sbuf);

    for (int l = 0; l < 3; ++l) {
        float* s1h = sbuf + l * SL;
        float* s2h = s1h + SH;
        float* s1o = s2h + SH;
        float* s2o = s1o + SO;

        // ---- head GAT: G=8, O=32 ----
        gemm_wave<<<dim3((Bc * Nn) / 64, Ff / 32), 256, 0, stream>>>(
            Af_a, WTF + (size_t)(2 * l) * Ff * Ff,
            a_heads + (size_t)l * Hh * 2 * Oo, WhFrag, s1h, s2h, Hh, Oo, 5);
        attn_kernel<2, 4, false, false><<<dim3(Nn / 32, 1, Bc * Hh), 256, 0, stream>>>(
            WhFrag, s1h, s2h, maskT, nullptr, Af_b);

        // ---- out GAT: G=1, O=F=256 ----
        gemm_wave<<<dim3((Bc * Nn) / 64, Ff / 32), 256, 0, stream>>>(
            Af_b, WTF + (size_t)(2 * l + 1) * Ff * Ff,
            a_out + (size_t)l * 2 * Ff, WhFrag, s1o, s2o, 1, Ff, 8);
        if (l == 2) {
            attn_kernel<4, 8, true, true><<<dim3(Nn / 32, Ff / 128, Bc), 512, 0, stream>>>(
                WhFrag, s1o, s2o, maskT, out, nullptr);
        } else {
            attn_kernel<4, 8, true, false><<<dim3(Nn / 32, Ff / 128, Bc), 512, 0, stream>>>(
                WhFrag, s1o, s2o, maskT, nullptr, Af_a);
        }
    }
}

// Round 8
// 257.058 us; speedup vs baseline: 1.4187x; 1.0891x over previous
//
#include <hip/hip_runtime.h>
#include <math.h>

#if __has_builtin(__builtin_amdgcn_exp2f)
#define EXP2(x) __builtin_amdgcn_exp2f(x)
#else
#define EXP2(x) exp2f(x)
#endif

#define ALPHA_LRELU 0.2f
#define LOG2E 1.4426950408889634f
#define ESHIFT 6.0f
#define BIGM 1024.0f  // bit=0 -> exp2 arg < -1000 -> p = 0

constexpr int Bc = 2, Nn = 2048, Ff = 256, Hh = 8, Oo = 32;

typedef _Float16 f16;
typedef f16 f16x8 __attribute__((ext_vector_type(8)));
typedef f16 f16x4 __attribute__((ext_vector_type(4)));
typedef float f32x4 __attribute__((ext_vector_type(4)));
typedef unsigned long long u64;
typedef unsigned u32;

// ---------------------------------------------------------------------------
// Fused prep: zero s-bufs; B<768: adj->maskT; 768..895: apack x;
// 896..1023: weights -> B-frag WTF.  (R1-measured, unchanged.)
// ---------------------------------------------------------------------------
__global__ __launch_bounds__(256) void prep_kernel(
    const int* __restrict__ adj, const float* __restrict__ x,
    const float* __restrict__ W_heads, const float* __restrict__ W_out,
    u32* __restrict__ maskT, f16* __restrict__ Af, f16* __restrict__ WTF,
    float* __restrict__ sbuf) {
    const int B = blockIdx.x;
    const int t = threadIdx.x;
    int g = B * 256 + t;
    if (g < 221184) sbuf[g] = 0.f;  // 3 * (2*SH + 2*SO)

    if (B < 768) {
        for (int idx = g; idx < Bc * Nn * Nn; idx += 768 * 256) {
            u64 bl = __ballot(adj[idx] != 0);
            int lane = t & 63;
            int i = (idx >> 11) & 2047;
            int b = idx >> 22;
            int c32 = ((idx & 2047) & ~63) >> 5;
            if (lane == 0)
                maskT[((size_t)b * 64 + c32) * 2048 + i] = (u32)bl;
            else if (lane == 1)
                maskT[((size_t)b * 64 + c32 + 1) * 2048 + i] = (u32)(bl >> 32);
        }
    } else if (B < 896) {
        int w = t >> 6, lane = t & 63;
        int am = lane & 15, aq = lane >> 4;
#pragma unroll
        for (int it = 0; it < 4; ++it) {
            int slot = (B - 768) * 4 + w + it * 512;
            int mt = slot >> 3, c = slot & 7;
            const float* ap = x + ((size_t)mt * 16 + am) * Ff + c * 32 + aq * 8;
            f32x4 v0 = *(const f32x4*)ap;
            f32x4 v1 = *(const f32x4*)(ap + 4);
            f16x8 o;
#pragma unroll
            for (int i = 0; i < 4; ++i) { o[i] = (f16)v0[i]; o[4 + i] = (f16)v1[i]; }
            *(f16x8*)&Af[(size_t)slot * 512 + lane * 8] = o;
        }
    } else {
#pragma unroll
        for (int it = 0; it < 3; ++it) {
            int unit = (B - 896) * 3 + it;  // 0..383
            int y = unit >> 6, bx = unit & 63;
            int ll = y >> 1, st = y & 1;
            int col = bx * 4 + (t >> 6);
            int k0 = (t & 63) * 4;
            const float* src;
            int stride;
            if (st == 0) {
                src = W_heads + (((size_t)ll * Hh + (col >> 5)) * Ff) * Oo + (col & 31);
                stride = Oo;
            } else {
                src = W_out + (size_t)ll * Ff * Ff + col;
                stride = Ff;
            }
            f16x4 v;
#pragma unroll
            for (int i = 0; i < 4; ++i) v[i] = (f16)src[(size_t)(k0 + i) * stride];
            int cg = col >> 4, am = col & 15;
            int c = k0 >> 5, aq = (k0 >> 3) & 3, i0 = k0 & 7;
            *(f16x4*)&WTF[(((size_t)y * 16 + cg) * 8 + c) * 512 +
                          (aq * 16 + am) * 8 + i0] = v;
        }
    }
}

// ---------------------------------------------------------------------------
// Frag GEMM: wave = 16 rows x 32 cols (2 cg), FULL-PRELOAD (8 A + 16 B
// frags). Grid (64, 8). Epilogue: 2 WhFrag writes + s1/s2.
// R8 deltas vs R1 (both verified-correct in R3/R5/R7 runs):
//   - s2 pre-scaled by LOG2E (saves one mul/k in attn)
//   - head (G=8): single writer per s-slot -> plain store (no atomics)
// ---------------------------------------------------------------------------
__global__ __launch_bounds__(256) void gemm_wave(
    const f16* __restrict__ Af, const f16* __restrict__ WTF,
    const float* __restrict__ pa, f16* __restrict__ WhFrag,
    float* __restrict__ s1, float* __restrict__ s2,
    int G, int Ofull, int oshift) {
    int t = threadIdx.x;
    int w = t >> 6, lane = t & 63;
    int am = lane & 15, aq = lane >> 4;
    int mt = blockIdx.x * 4 + w;
    int colb = blockIdx.y * 32;

    const f16* ap = Af + (size_t)(mt * 8) * 512 + lane * 8;
    const f16* bp0 = WTF + (size_t)((colb >> 4) * 8) * 512 + lane * 8;
    const f16* bp1 = bp0 + 8 * 512;

    f16x8 av[8], bv0[8], bv1[8];
#pragma unroll
    for (int c = 0; c < 8; ++c) {
        av[c] = *(const f16x8*)(ap + c * 512);
        bv0[c] = *(const f16x8*)(bp0 + c * 512);
        bv1[c] = *(const f16x8*)(bp1 + c * 512);
    }
    f32x4 acc0 = {0.f, 0.f, 0.f, 0.f}, acc1 = acc0;
#pragma unroll
    for (int c = 0; c < 8; ++c) {
        acc0 = __builtin_amdgcn_mfma_f32_16x16x32_f16(av[c], bv0[c], acc0, 0, 0, 0);
        acc1 = __builtin_amdgcn_mfma_f32_16x16x32_f16(av[c], bv1[c], acc1, 0, 0, 0);
    }

    int m0 = mt * 16;
    int b = m0 >> 11;
    int nn0 = (m0 & 2047) + aq * 4;
    int cO = (m0 & 2047) >> 5;
    int aq_p = ((mt & 1) << 1) | (aq >> 1);
    int i0p = (aq & 1) << 2;
    int g = colb >> oshift;  // 32 cols within one g (head: colb mult of 32)
    size_t bg = (size_t)b * G + g;
    int cg = (colb & (Ofull - 1)) >> 4;

    f16x4 c40, c41;
#pragma unroll
    for (int e = 0; e < 4; ++e) { c40[e] = (f16)acc0[e]; c41[e] = (f16)acc1[e]; }
    *(f16x4*)&WhFrag[(((bg * (Ofull >> 4) + cg) * 64 + cO) * 512) +
                     (aq_p * 16 + am) * 8 + i0p] = c40;
    *(f16x4*)&WhFrag[(((bg * (Ofull >> 4) + cg + 1) * 64 + cO) * 512) +
                     (aq_p * 16 + am) * 8 + i0p] = c41;

    int o0 = (colb & (Ofull - 1)) + am;
    const float* a1p = pa + 2 * (size_t)g * Ofull;
    float a10 = a1p[o0], a11 = a1p[o0 + 16];
    float a20 = a1p[Ofull + o0], a21 = a1p[Ofull + o0 + 16];
#pragma unroll
    for (int e = 0; e < 4; ++e) {
        float p1 = acc0[e] * a10 + acc1[e] * a11;
        float p2 = acc0[e] * a20 + acc1[e] * a21;
#pragma unroll
        for (int s = 1; s < 16; s <<= 1) {
            p1 += __shfl_xor(p1, s);
            p2 += __shfl_xor(p2, s);
        }
        if (am == 0) {
            size_t sidx = bg * Nn + nn0 + e;
            if (G == 1) {
                atomicAdd(&s1[sidx], p1);
                atomicAdd(&s2[sidx], p2 * LOG2E);
            } else {  // single writer per slot for head GEMM
                s1[sidx] = p1;
                s2[sidx] = p2 * LOG2E;
            }
        }
    }
}

// ---------------------------------------------------------------------------
// Attention (EXACT R1-measured inner loop): NW waves = (NW/4 col-halves) x
// (4 j-slices); each wave = 2 row-tiles (32 rows) x CGW*16 cols, prefetch-2,
// e-in-registers.  Head: NW=4, CGW=2, grid (64,1,16).  Out: NW=8, CGW=4,
// grid (64,2,2), 512 thr.  s2 arrives pre-scaled by LOG2E (gemm-side);
// the chain is otherwise byte-for-byte the R1 formulation: scalar lacc,
// BIGM-fma masking, end shuffles, rli hoist.  (R6/R7's ones-MFMA and
// post-exp AND-mask REGRESSED +21us -- reverted.)
// ---------------------------------------------------------------------------
template <int CGW, int NW, bool OUT, bool FINAL>
__global__ __launch_bounds__(NW * 64) void attn_kernel(
    const f16* __restrict__ WhFrag, const float* __restrict__ s1,
    const float* __restrict__ s2, const u32* __restrict__ maskT,
    float* __restrict__ dst, f16* __restrict__ AfOut) {
    constexpr float C0 = -ESHIFT * LOG2E - BIGM;
    constexpr float C08 = (1.0f - ALPHA_LRELU) * C0;
    constexpr int NCG = OUT ? 16 : 2;
    constexpr int COLS = (NW / 4) * CGW * 16;  // block col coverage
    constexpr int TSTR = COLS + 8;             // f16 LDS row stride, 16B-aligned
    __shared__ float Ls[NW][2][64];
    __shared__ float As[NW][64][2 * CGW * 4];
    __shared__ f16 T[2][16 * TSTR];

    int t = threadIdx.x;
    int w = t >> 6, lane = t & 63;
    int am = lane & 15, aq = lane >> 4;
    int ch = w >> 2;   // col-half
    int js = w & 3;    // j-slice
    int i0 = blockIdx.x * 32;
    int bz = blockIdx.z;
    int b = OUT ? bz : (bz >> 3);
    int cg0 = OUT ? blockIdx.y * ((NW / 4) * CGW) + ch * CGW : 0;
    int dstcol = OUT ? cg0 * 16 : (bz & 7) * Oo;

    const f16* bp[CGW];
#pragma unroll
    for (int i = 0; i < CGW; ++i)
        bp[i] = WhFrag + ((size_t)bz * NCG + cg0 + i) * 64 * 512 + lane * 8;
    const float* s2p = s2 + (size_t)bz * Nn + aq * 8;  // pre-scaled by LOG2E
    float s1c0 = fmaf(s1[(size_t)bz * Nn + i0 + am], LOG2E, C0);
    float s1c1 = fmaf(s1[(size_t)bz * Nn + i0 + 16 + am], LOG2E, C0);
    const u32* mtp0 = maskT + (size_t)b * 64 * 2048 + i0 + am;
    const u32* mtp1 = mtp0 + 16;

    f32x4 acc[2][CGW] = {};
    float lacc0 = 0.f, lacc1 = 0.f;

    int cbeg = js * 16, cend = cbeg + 16;  // this wave's j-slice (16 chunks)

    f16x8 xb[CGW], yb[CGW];
    f32x4 xv0, xv1, yv0, yv1;
    u32 xm0, xm1, ym0, ym1;
    auto ld = [&](int c, f16x8 (&bb)[CGW], f32x4& v0, f32x4& v1,
                  u32& m0, u32& m1) {
#pragma unroll
        for (int i = 0; i < CGW; ++i) bb[i] = *(const f16x8*)(bp[i] + c * 512);
        v0 = *(const f32x4*)(s2p + c * 32);
        v1 = *(const f32x4*)(s2p + c * 32 + 4);
        m0 = mtp0[c * 2048];
        m1 = mtp1[c * 2048];
    };
    auto comp = [&](f16x8 (&bb)[CGW], f32x4 v0, f32x4 v1, u32 m0, u32 m1) {
        u32 bits0 = (m0 >> (aq * 8)) & 0xffu;
        u32 bits1 = (m1 >> (aq * 8)) & 0xffu;
        f16x8 af0, af1;
#pragma unroll
        for (int k = 0; k < 8; ++k) {
            float sv = (k < 4 ? v0[k] : v1[k - 4]);  // already * LOG2E
            float u0 = s1c0 + sv;
            float u1 = s1c1 + sv;
            float lr0 = fmaxf(u0, fmaf(ALPHA_LRELU, u0, C08));
            float lr1 = fmaxf(u1, fmaf(ALPHA_LRELU, u1, C08));
            float bf0 = (float)((bits0 >> k) & 1u);
            float bf1 = (float)((bits1 >> k) & 1u);
            float p0 = EXP2(fmaf(bf0, BIGM, lr0));
            float p1 = EXP2(fmaf(bf1, BIGM, lr1));
            lacc0 += p0;
            lacc1 += p1;
            af0[k] = (f16)p0;
            af1[k] = (f16)p1;
        }
#pragma unroll
        for (int i = 0; i < CGW; ++i) {
            acc[0][i] = __builtin_amdgcn_mfma_f32_16x16x32_f16(af0, bb[i], acc[0][i], 0, 0, 0);
            acc[1][i] = __builtin_amdgcn_mfma_f32_16x16x32_f16(af1, bb[i], acc[1][i], 0, 0, 0);
        }
    };

    ld(cbeg, xb, xv0, xv1, xm0, xm1);
    ld(cbeg + 1, yb, yv0, yv1, ym0, ym1);
    for (int c = cbeg; c < cend; c += 2) {
        comp(xb, xv0, xv1, xm0, xm1);
        ld(c + 2 < cend ? c + 2 : cbeg, xb, xv0, xv1, xm0, xm1);
        comp(yb, yv0, yv1, ym0, ym1);
        ld(c + 3 < cend ? c + 3 : cbeg, yb, yv0, yv1, ym0, ym1);
    }

    // intra-wave l: sum over aq groups -> lane holds l_slice[am] per tile
    lacc0 += __shfl_xor(lacc0, 16);
    lacc0 += __shfl_xor(lacc0, 32);
    lacc1 += __shfl_xor(lacc1, 16);
    lacc1 += __shfl_xor(lacc1, 32);

    Ls[w][0][lane] = lacc0;
    Ls[w][1][lane] = lacc1;
#pragma unroll
    for (int tt = 0; tt < 2; ++tt)
#pragma unroll
        for (int i = 0; i < CGW; ++i)
#pragma unroll
            for (int e = 0; e < 4; ++e)
                As[w][lane][tt * CGW * 4 + i * 4 + e] = acc[tt][i][e];
    __syncthreads();

    if ((w & 3) < 2) {  // wave (ch, tt=js) finishes row tile tt for its cols
        int tt = w & 3;
        float lt = Ls[ch * 4 + 0][tt][lane] + Ls[ch * 4 + 1][tt][lane] +
                   Ls[ch * 4 + 2][tt][lane] + Ls[ch * 4 + 3][tt][lane];
        // per-row reciprocals hoisted out of the i-loop (li invariant in i)
        float rli[4];
#pragma unroll
        for (int e = 0; e < 4; ++e) rli[e] = 1.0f / __shfl(lt, aq * 4 + e);
        f16* Tw = T[tt];
#pragma unroll
        for (int i = 0; i < CGW; ++i) {
            f32x4 a;
#pragma unroll
            for (int e = 0; e < 4; ++e)
                a[e] = As[ch * 4 + 0][lane][tt * CGW * 4 + i * 4 + e] +
                       As[ch * 4 + 1][lane][tt * CGW * 4 + i * 4 + e] +
                       As[ch * 4 + 2][lane][tt * CGW * 4 + i * 4 + e] +
                       As[ch * 4 + 3][lane][tt * CGW * 4 + i * 4 + e];
#pragma unroll
            for (int e = 0; e < 4; ++e) {
                int r = aq * 4 + e;             // C/D: col=am, row=aq*4+e
                float v = a[e] * rli[e];
                v = v > 0.f ? v : __expf(v) - 1.f;
                if (OUT) v = v > 0.f ? v : __expf(v) - 1.f;
                if (FINAL) {
                    dst[((size_t)b * Nn + i0 + tt * 16 + r) * Ff + dstcol +
                        i * 16 + am] = v;
                } else {
                    Tw[r * TSTR + ch * CGW * 16 + i * 16 + am] = (f16)v;
                }
            }
        }
        if (!FINAL) {
            // in-wave read-back in A-frag order (no barrier: same wave's data)
            int mt = (b * Nn + i0 + tt * 16) >> 4;  // GLOBAL row tile
#pragma unroll
            for (int s = 0; s < CGW / 2; ++s) {
                f16x8 o = *(const f16x8*)&Tw[am * TSTR + ch * CGW * 16 +
                                             s * 32 + aq * 8];
                int c = (dstcol >> 5) + s;
                *(f16x8*)&AfOut[(size_t)(mt * 8 + c) * 512 + lane * 8] = o;
            }
        }
    }
}

// ---------------------------------------------------------------------------
extern "C" void kernel_launch(void* const* d_in, const int* in_sizes, int n_in,
                              void* d_out, int out_size, void* d_ws, size_t ws_size,
                              hipStream_t stream) {
    const float* x = (const float*)d_in[0];
    const int* adj = (const int*)d_in[1];
    const float* W_heads = (const float*)d_in[2];
    const float* a_heads = (const float*)d_in[3];
    const float* W_out = (const float*)d_in[4];
    const float* a_out = (const float*)d_in[5];
    float* out = (float*)d_out;

    float* ws = (float*)d_ws;
    const size_t M = (size_t)Bc * Nn * Ff;        // 1,048,576
    f16* Af_a = (f16*)ws;                         // M f16
    f16* Af_b = (f16*)(ws + M / 2);               // M f16
    f16* WhFrag = (f16*)(ws + M);                 // M f16
    u32* maskT = (u32*)(ws + 3 * M / 2);          // 1 MB
    f16* WTF = (f16*)(ws + 3 * M / 2 + M / 4);    // 6*F*F f16 = 196608 floats
    float* sbuf = ws + 3 * M / 2 + M / 4 + 196608;
    const size_t SH = (size_t)Bc * Hh * Nn;       // 32768
    const size_t SO = (size_t)Bc * Nn;            // 4096
    const size_t SL = 2 * SH + 2 * SO;

    prep_kernel<<<1024, 256, 0, stream>>>(adj, x, W_heads, W_out,
                                          maskT, Af_a, WTF, sbuf);

    for (int l = 0; l < 3; ++l) {
        float* s1h = sbuf + l * SL;
        float* s2h = s1h + SH;
        float* s1o = s2h + SH;
        float* s2o = s1o + SO;

        // ---- head GAT: G=8, O=32 ----
        gemm_wave<<<dim3((Bc * Nn) / 64, Ff / 32), 256, 0, stream>>>(
            Af_a, WTF + (size_t)(2 * l) * Ff * Ff,
            a_heads + (size_t)l * Hh * 2 * Oo, WhFrag, s1h, s2h, Hh, Oo, 5);
        attn_kernel<2, 4, false, false><<<dim3(Nn / 32, 1, Bc * Hh), 256, 0, stream>>>(
            WhFrag, s1h, s2h, maskT, nullptr, Af_b);

        // ---- out GAT: G=1, O=F=256 ----
        gemm_wave<<<dim3((Bc * Nn) / 64, Ff / 32), 256, 0, stream>>>(
            Af_b, WTF + (size_t)(2 * l + 1) * Ff * Ff,
            a_out + (size_t)l * 2 * Ff, WhFrag, s1o, s2o, 1, Ff, 8);
        if (l == 2) {
            attn_kernel<4, 8, true, true><<<dim3(Nn / 32, Ff / 128, Bc), 512, 0, stream>>>(
                WhFrag, s1o, s2o, maskT, out, nullptr);
        } else {
            attn_kernel<4, 8, true, false><<<dim3(Nn / 32, Ff / 128, Bc), 512, 0, stream>>>(
                WhFrag, s1o, s2o, maskT, nullptr, Af_a);
        }
    }
}